// Round 11
// baseline (306.186 us; speedup 1.0000x reference)
//
#include <hip/hip_runtime.h>
#include <hip/hip_bf16.h>

// IO-HMM fwd/bwd chain + projection for MI355X (gfx950).
// L=256 steps, B=128 batch, S=256 states, NL=64 labels.
//
// Kernel 1 (chain): R21 = R13 geometry (4 waves x 4 M-tiles, T fully in
//   regs: a_hi[4][8]=128 VGPR) + R18b clean-store mechanism + proper
//   register budget. Ledger: R13's 2350cyc/step carried 4 scatter stores
//   (~4x280=1120cyc retire tail, per R18b's measured store cost) and a
//   140-VGPR budget; corrected, clean 4x4 projects ~1230cyc < R18b's 1720
//   (which pays the 16-wave 128KB/step carry broadcast ~1024cyc service;
//   4x4 pays only 32KB). R20 (b128+conflicts, neutral) showed the 16-wave
//   LDS phase has slack -- instruction count is not the lever; BYTES are.
//   Components here: frag reads 16 b64/wave (verified conflict-free
//   stride-67 layout), 32 MFMA/wave in 4 independent 8-deep chains, em
//   prefetch depth 1, deferred coalesced stores (wave stores 4 batch-rows
//   as 4x512B lane-linear stores from the exchange plane), 1 barrier/step.
//   launch_bounds(256,1): ~240 VGPR, no spill. Arithmetic = R18b exactly
//   (absmax 128 expected). If this regresses to ~R18b: TLP is the binding
//   resource at every traffic level -> R18b structure is the optimum.
// Kernel 2 (score): R11 version unchanged (gap is timed-region overhead).

typedef _Float16 half8 __attribute__((ext_vector_type(8)));
typedef _Float16 half4 __attribute__((ext_vector_type(4)));
typedef float    f32x4 __attribute__((ext_vector_type(4)));
typedef unsigned long long u64;

#define LL 256
#define BB 128
#define SS 256
#define BT 16
#define RSTR8 67   // carry/p-plane row stride in 8B units (ODD -> conflict-free)
#define RSTRO 65   // o-plane row stride in 8B units (ODD -> conflict-free)

static __device__ __forceinline__ f32x4 mfma16f(half8 a, half8 b, f32x4 c) {
  return __builtin_amdgcn_mfma_f32_16x16x32_f16(a, b, c, 0, 0, 0);
}

// LDS-only barrier: order ds ops, leave vmcnt (global loads/stores) in flight.
static __device__ __forceinline__ void lds_barrier() {
  __asm__ __volatile__("s_waitcnt lgkmcnt(0)\n\ts_barrier" ::: "memory");
}

// Round-to-nearest-even f16 pack (NOT cvt_pkrtz -- RTZ bias compounds over
// the 255-step chain into ~6% coherent shrink; R8 erratum).
static __device__ __forceinline__ u64 pack4(f32x4 v) {
  union { half4 h; u64 u; } x;
  x.h[0] = (_Float16)v[0];
  x.h[1] = (_Float16)v[1];
  x.h[2] = (_Float16)v[2];
  x.h[3] = (_Float16)v[3];
  return x.u;
}

// 16B logical fragment as two b64 reads (8B-aligned odd-stride layout).
static __device__ __forceinline__ half8 read_frag_s(const u64* plane, int row,
                                                    int kt, int q, int stride8) {
  const int o = row * stride8 + kt * 8 + q * 2;
  union { u64 u[2]; half8 v; } x;
  x.u[0] = plane[o];
  x.u[1] = plane[o + 1];
  return x.v;
}

__global__ __launch_bounds__(256, 1)
void hmm_chain(const int* __restrict__ sent, const float* __restrict__ emb,
               const float* __restrict__ T, _Float16* __restrict__ fwh,
               _Float16* __restrict__ gh)
{
  __shared__ u64 s_carry[2][BT * RSTR8]; // [buf][row*stride], single f16 plane
  __shared__ u64 v_pl[2][BT * RSTR8];    // bwd: pack4(v) mirror plane, dbuf
  __shared__ int s_tok[BT * 257];        // [batch][l], stride 257

  const int tid  = threadIdx.x;
  const int lane = tid & 63;
  const int w    = tid >> 6;   // wave 0..3 -> states [64w, 64w+64)
  const int m    = lane & 15;  // A row-in-tile / B col (= batch)
  const int q    = lane >> 4;  // quad

  const int  bid = blockIdx.x;
  const bool fwd = (bid < 8);
  const int  bg0 = (fwd ? bid : bid - 8) * BT;
  _Float16* const obuf = fwd ? fwh : gh;

  // ---- stage sentence tokens ----
  for (int idx = tid; idx < BT * LL; idx += 256) {
    int bb = idx >> 8, l2 = idx & 255;
    s_tok[bb * 257 + l2] = sent[(bg0 + bb) * LL + l2];
  }
  __syncthreads();

  // ---- load T fragments (A operand), 4 M-tiles x 8 K-frags = 128 regs
  half8 a_hi[4][8];
#pragma unroll
  for (int tt = 0; tt < 4; ++tt) {
    const int r0 = 64 * w + 16 * tt + m;   // state (M index)
#pragma unroll
    for (int kt = 0; kt < 8; ++kt) {
      const int kb = 32 * kt + 8 * q;      // k base
      float v[8];
      if (fwd) {
        f32x4 f0 = *(const f32x4*)(T + r0 * 256 + kb);
        f32x4 f1 = *(const f32x4*)(T + r0 * 256 + kb + 4);
#pragma unroll
        for (int j = 0; j < 4; ++j) { v[j] = f0[j]; v[4 + j] = f1[j]; }
      } else {
#pragma unroll
        for (int j = 0; j < 8; ++j) v[j] = T[(kb + j) * 256 + r0]; // T^T
      }
      half8 hi;
#pragma unroll
      for (int j = 0; j < 8; ++j) hi[j] = (_Float16)v[j];   // RNE
      a_hi[tt][kt] = hi;
    }
  }

  // ---- init carry at l0; bwd also inits v_pl[0] = 1 (step-0 output g[l0])
  const int l0 = fwd ? 0 : (LL - 1);
  {
    const int tok0 = s_tok[m * 257 + l0];
    f32x4 one = 1.0f;
    const u64 pone = pack4(one);
#pragma unroll
    for (int tt = 0; tt < 4; ++tt) {
      const int st = 64 * w + 16 * tt + 4 * q;    // this lane's first state
      f32x4 e0 = *(const f32x4*)(emb + (size_t)tok0 * 256 + st);
      u64 pc = pack4(e0);                         // carry = em[l0] both dirs
      s_carry[0][m * RSTR8 + 16 * w + 4 * tt + q] = pc;
      if (!fwd) v_pl[0][m * RSTR8 + 16 * w + 4 * tt + q] = pone;  // g=1
    }
  }

  // ---- prefetch em for step 1 (4 tiles) ----
  f32x4 em_pref[4];
  {
    const int l1 = fwd ? 1 : (LL - 2);
    const int tok1 = s_tok[m * 257 + l1];
#pragma unroll
    for (int tt = 0; tt < 4; ++tt)
      em_pref[tt] = *(const f32x4*)(emb + (size_t)tok1 * 256 + 64 * w + 16 * tt + 4 * q);
  }
  __syncthreads();

  // ---- main chain ----
  // Step s stores step s-1's output COALESCED: wave w reads batch-rows
  // {4w..4w+3} of the s-1 output plane (fwd: carry; bwd: v_pl) lane-linear
  // and issues four 512B stores (8 full lines each).
  for (int s = 1; s < LL; ++s) {
    const int lp = fwd ? (s - 1) : (LL - s);   // prev step's l
    const int rb = (s - 1) & 1, wb = s & 1;

    const u64* pr = &s_carry[rb][0];
    half8 bfr[8];
#pragma unroll
    for (int kt = 0; kt < 8; ++kt)
      bfr[kt] = read_frag_s(pr, m, kt, q, RSTR8);

    // deferred out-row reads for step s-1 (coalesced stores issued below)
    const u64* op = fwd ? &s_carry[rb][0] : &v_pl[rb][0];
    u64 ov[4];
#pragma unroll
    for (int j = 0; j < 4; ++j)
      ov[j] = op[(4 * w + j) * RSTR8 + lane];

    // consume prefetched em; issue next prefetch (token from LDS)
    f32x4 em_now[4];
#pragma unroll
    for (int tt = 0; tt < 4; ++tt) em_now[tt] = em_pref[tt];
    {
      const int ln = fwd ? (s + 1 < LL ? s + 1 : LL - 1)
                         : ((LL - 2) - s > 0 ? (LL - 2) - s : 0);
      const int tokn = s_tok[m * 257 + ln];
#pragma unroll
      for (int tt = 0; tt < 4; ++tt)
        em_pref[tt] = *(const f32x4*)(emb + (size_t)tokn * 256 + 64 * w + 16 * tt + 4 * q);
    }

    // single-product f16 matmul: 32 MFMA/wave/step, 4 independent 8-deep
    // chains; B-frags read ONCE, reused across the 4 M-tiles (the 4x
    // LDS-broadcast cut: 32KB/step/CU instead of 128KB).
    f32x4 acc[4];
#pragma unroll
    for (int tt = 0; tt < 4; ++tt) acc[tt] = 0.0f;
#pragma unroll
    for (int kt = 0; kt < 8; ++kt)
#pragma unroll
      for (int tt = 0; tt < 4; ++tt)
        acc[tt] = mfma16f(a_hi[tt][kt], bfr[kt], acc[tt]);

#pragma unroll
    for (int tt = 0; tt < 4; ++tt) {
      f32x4 cn = acc[tt] * em_now[tt];    // new carry
      u64 p0 = pack4(cn);
      s_carry[wb][m * RSTR8 + 16 * w + 4 * tt + q] = p0;
      if (!fwd)
        v_pl[wb][m * RSTR8 + 16 * w + 4 * tt + q] = pack4(acc[tt]); // g=v
    }

    // coalesced 512B stores of the previous step's rows (8 full lines each)
    _Float16* orow = obuf + ((size_t)lp * BB + bg0) * SS;
#pragma unroll
    for (int j = 0; j < 4; ++j)
      *(u64*)(orow + (size_t)(4 * w + j) * SS + lane * 4) = ov[j];

    lds_barrier();  // LDS ordering only; global stores/loads stay in flight
  }

  // ---- epilogue: store the final step's rows (plane 1 = step 255) ----
  {
    const int lp = fwd ? (LL - 1) : 0;
    const u64* op = fwd ? &s_carry[1][0] : &v_pl[1][0];
    _Float16* orow = obuf + ((size_t)lp * BB + bg0) * SS;
#pragma unroll
    for (int j = 0; j < 4; ++j) {
      u64 ov = op[(4 * w + j) * RSTR8 + lane];
      *(u64*)(orow + (size_t)(4 * w + j) * SS + lane * 4) = ov;
    }
  }
}

__global__ __launch_bounds__(256, 2)
void hmm_score(const _Float16* __restrict__ fwh, const _Float16* __restrict__ gh,
               const float* __restrict__ outm, float* __restrict__ score)
{
  __shared__ u64 p_pl[64 * RSTR8];   // p = fw*g, [row][k] f16
  __shared__ u64 o_pl[64 * RSTRO];   // outm^T,   [n][k]  f16

  const int tid  = threadIdx.x;
  const int lane = tid & 63;
  const int w    = tid >> 6;
  const int rh   = w >> 1;     // row half: rows [32rh, 32rh+32)
  const int np   = w & 1;      // n-pair: n-tiles {2np, 2np+1}
  const int m    = lane & 15;
  const int q    = lane >> 4;
  const int R0   = blockIdx.x * 64;  // row = l*128 + b

  // ---- stage outm -> o_pl[n][k] f16 (RNE, hi only), coalesced f32x4 loads
  {
    _Float16* o_h = (_Float16*)o_pl;
    for (int i = tid; i < 4096; i += 256) {
      f32x4 v = *(const f32x4*)(outm + i * 4);   // flat = k*64+n
      int k = i >> 4, n0 = (i & 15) * 4;
#pragma unroll
      for (int r = 0; r < 4; ++r)
        o_h[(n0 + r) * (RSTRO * 4) + k] = (_Float16)v[r];
    }
  }

  // ---- stage p = fw * g (f16 packed mul, RNE) ----
  for (int idx = tid; idx < 64 * 64; idx += 256) {
    int row = idx >> 6, c = idx & 63;       // c = 8B column index
    union { u64 u; half4 h; } a, b, p;
    a.u = *(const u64*)(fwh + (size_t)(R0 + row) * 256 + c * 4);
    b.u = *(const u64*)(gh  + (size_t)(R0 + row) * 256 + c * 4);
    p.h = a.h * b.h;                        // v_pk_mul_f16 x2
    p_pl[row * RSTR8 + c] = p.u;
  }
  lds_barrier();

  f32x4 acc[2][2];
#pragma unroll
  for (int j = 0; j < 2; ++j)
#pragma unroll
    for (int jn = 0; jn < 2; ++jn) acc[j][jn] = 0.0f;

#pragma unroll
  for (int kt = 0; kt < 8; ++kt) {
    half8 of[2];
#pragma unroll
    for (int jn = 0; jn < 2; ++jn)
      of[jn] = read_frag_s(o_pl, 16 * (2 * np + jn) + m, kt, q, RSTRO);
#pragma unroll
    for (int j = 0; j < 2; ++j) {
      half8 pf = read_frag_s(p_pl, 32 * rh + 16 * j + m, kt, q, RSTR8);
#pragma unroll
      for (int jn = 0; jn < 2; ++jn)
        acc[j][jn] = mfma16f(pf, of[jn], acc[j][jn]);
    }
  }

#pragma unroll
  for (int j = 0; j < 2; ++j) {
#pragma unroll
    for (int jn = 0; jn < 2; ++jn) {
#pragma unroll
      for (int r = 0; r < 4; ++r) {
        int row = R0 + 32 * rh + 16 * j + 4 * q + r;
        int l = row >> 7, b = row & 127;
        score[(size_t)b * 16384 + l * 64 + 16 * (2 * np + jn) + m] = acc[j][jn][r];
      }
    }
  }
}

extern "C" void kernel_launch(void* const* d_in, const int* in_sizes, int n_in,
                              void* d_out, int out_size, void* d_ws, size_t ws_size,
                              hipStream_t stream) {
  (void)in_sizes; (void)n_in; (void)out_size; (void)ws_size;
  const int*   sent = (const int*)d_in[0];
  const float* emb  = (const float*)d_in[1];
  const float* T    = (const float*)d_in[2];
  const float* outm = (const float*)d_in[3];
  _Float16* fwh = (_Float16*)d_ws;                  // [L][B][S] f16, 16 MB
  _Float16* gh  = fwh + (size_t)LL * BB * SS;       // [L][B][S] f16, 16 MB

  hmm_chain<<<16, 256, 0, stream>>>(sent, emb, T, fwh, gh);
  hmm_score<<<512, 256, 0, stream>>>(fwh, gh, outm, (float*)d_out);
}

// Round 12
// 273.934 us; speedup vs baseline: 1.1177x; 1.1177x over previous
//
#include <hip/hip_runtime.h>
#include <hip/hip_bf16.h>

// IO-HMM fwd/bwd chain + projection for MI355X (gfx950).
// L=256 steps, B=128 batch, S=256 states, NL=64 labels.
//
// Kernel 1 (chain): R22 = R18b structure (16 waves x 1 M-tile, deferred
//   coalesced stores; geometry sweep complete: 16x1=183us < 4x4=227 <
//   8x2=247 with clean stores -> TLP binds, 16-wave wins) + BATCH SPLIT:
//   BT=8, 32 blocks (16 fwd + 16 bwd) instead of BT=16 x 16 blocks.
//   Batch chains are independent; we were using 16 of 256 CUs. The LDS
//   broadcast (the dominant step phase, ~1030cyc at BT=16: 16 waves x
//   BT x 512B) halves: duplicate lanes (m>=8) read carry row m&7 --
//   same-address LDS reads BROADCAST at no bank cost (guide §2). MFMA
//   N-tiles are half-occupied (junk batch cols 8-15, never stored) --
//   MFMA is ~27% of busy cycles, wasting lanes there is free.
//   Carry/v_pl writes stay unmasked (rows 8-15 = copies; bank pattern
//   identical to R18b's verified 0-conflict layout). Output stores and
//   ov reads masked to w<8 (wave-uniform). Arithmetic per valid batch
//   element bit-identical to R18b (absmax 128 expected).
//   If this lands: BT=4/64 blocks next. If neutral: residual is barrier/
//   fixed overhead, not LDS service.
// Kernel 2 (score): R11 version unchanged (gap is timed-region overhead).

typedef _Float16 half8 __attribute__((ext_vector_type(8)));
typedef _Float16 half4 __attribute__((ext_vector_type(4)));
typedef float    f32x4 __attribute__((ext_vector_type(4)));
typedef unsigned long long u64;

#define LL 256
#define BB 128
#define SS 256
#define BT 8      // batch rows per block (was 16) -- R22 split
#define NR 16     // plane rows (8 valid + 8 copy rows, keeps R18b bank layout)
#define RSTR8 67   // carry/p-plane row stride in 8B units (ODD -> conflict-free)
#define RSTRO 65   // o-plane row stride in 8B units (ODD -> conflict-free)

static __device__ __forceinline__ f32x4 mfma16f(half8 a, half8 b, f32x4 c) {
  return __builtin_amdgcn_mfma_f32_16x16x32_f16(a, b, c, 0, 0, 0);
}

// LDS-only barrier: order ds ops, leave vmcnt (global loads/stores) in flight.
static __device__ __forceinline__ void lds_barrier() {
  __asm__ __volatile__("s_waitcnt lgkmcnt(0)\n\ts_barrier" ::: "memory");
}

// Round-to-nearest-even f16 pack (NOT cvt_pkrtz -- RTZ bias compounds over
// the 255-step chain into ~6% coherent shrink; R8 erratum).
static __device__ __forceinline__ u64 pack4(f32x4 v) {
  union { half4 h; u64 u; } x;
  x.h[0] = (_Float16)v[0];
  x.h[1] = (_Float16)v[1];
  x.h[2] = (_Float16)v[2];
  x.h[3] = (_Float16)v[3];
  return x.u;
}

// 16B logical fragment as two b64 reads (8B-aligned odd-stride layout).
static __device__ __forceinline__ half8 read_frag_s(const u64* plane, int row,
                                                    int kt, int q, int stride8) {
  const int o = row * stride8 + kt * 8 + q * 2;
  union { u64 u[2]; half8 v; } x;
  x.u[0] = plane[o];
  x.u[1] = plane[o + 1];
  return x.v;
}

__global__ __launch_bounds__(1024, 4)
void hmm_chain(const int* __restrict__ sent, const float* __restrict__ emb,
               const float* __restrict__ T, _Float16* __restrict__ fwh,
               _Float16* __restrict__ gh)
{
  __shared__ u64 s_carry[2][NR * RSTR8]; // [buf][row*stride]; rows 8-15 = copies
  __shared__ u64 v_pl[2][NR * RSTR8];    // bwd: pack4(v) mirror plane, dbuf
  __shared__ int s_tok[BT * 257];        // [batch][l], stride 257

  const int tid  = threadIdx.x;
  const int lane = tid & 63;
  const int w    = tid >> 6;   // wave 0..15 -> states [16w, 16w+16)
  const int m    = lane & 15;  // A row-in-tile / B col (= batch, 8-15 junk)
  const int mr   = m & 7;      // valid batch row (duplicate lanes broadcast)
  const int q    = lane >> 4;  // quad

  const int  bid = blockIdx.x;
  const bool fwd = (bid < 16);
  const int  bg0 = (fwd ? bid : bid - 16) * BT;
  _Float16* const obuf = fwd ? fwh : gh;
  const int  st  = 16 * w + 4 * q;       // this lane's first state

  // ---- stage sentence tokens (BT=8 rows) ----
  for (int idx = tid; idx < BT * LL; idx += 1024) {
    int bb = idx >> 8, l2 = idx & 255;
    s_tok[bb * 257 + l2] = sent[(bg0 + bb) * LL + l2];
  }
  __syncthreads();

  // ---- load T fragments (A operand), single f16: 8 frags = 32 regs
  half8 a_hi[8];
#pragma unroll
  for (int kt = 0; kt < 8; ++kt) {
    const int r0 = 16 * w + m;           // state (M index)
    const int kb = 32 * kt + 8 * q;      // k base
    float v[8];
    if (fwd) {
      f32x4 f0 = *(const f32x4*)(T + r0 * 256 + kb);
      f32x4 f1 = *(const f32x4*)(T + r0 * 256 + kb + 4);
#pragma unroll
      for (int j = 0; j < 4; ++j) { v[j] = f0[j]; v[4 + j] = f1[j]; }
    } else {
#pragma unroll
      for (int j = 0; j < 8; ++j) v[j] = T[(kb + j) * 256 + r0]; // T^T
    }
    half8 hi;
#pragma unroll
    for (int j = 0; j < 8; ++j) hi[j] = (_Float16)v[j];   // RNE
    a_hi[kt] = hi;
  }

  // ---- init carry at l0; bwd also inits v_pl[0] = 1 (step-0 output g[l0])
  // All 16 rows written; rows 8-15 are copies of 0-7 (same loaded value).
  const int l0 = fwd ? 0 : (LL - 1);
  {
    const int tok0 = s_tok[mr * 257 + l0];
    f32x4 e0 = *(const f32x4*)(emb + (size_t)tok0 * 256 + st);
    u64 pc = pack4(e0);                       // carry = em[l0] both dirs
    s_carry[0][m * RSTR8 + 4 * w + q] = pc;
    if (!fwd) {
      f32x4 one = 1.0f;
      v_pl[0][m * RSTR8 + 4 * w + q] = pack4(one);  // g[L-1] = 1
    }
  }

  // ---- prefetch em for step 1 ----
  f32x4 em_pref;
  {
    const int l1 = fwd ? 1 : (LL - 2);
    const int tok1 = s_tok[mr * 257 + l1];
    em_pref = *(const f32x4*)(emb + (size_t)tok1 * 256 + st);
  }
  __syncthreads();

  // ---- main chain ----
  // B-frag reads hit rows 0-7 only (mr) -> duplicate lanes share addresses
  // -> LDS broadcast, distinct bytes HALVED vs BT=16. Step s stores step
  // s-1's batch-row w (w<8) as ONE lane-linear 512B store.
  for (int s = 1; s < LL; ++s) {
    const int lp = fwd ? (s - 1) : (LL - s);   // prev step's l
    const int rb = (s - 1) & 1, wb = s & 1;

    const u64* pr = &s_carry[rb][0];
    half8 bfr[8];
#pragma unroll
    for (int kt = 0; kt < 8; ++kt)
      bfr[kt] = read_frag_s(pr, mr, kt, q, RSTR8);   // broadcast pairs

    // deferred out-row read for step s-1 (w<8 only)
    const u64* op = fwd ? &s_carry[rb][0] : &v_pl[rb][0];
    u64 ov = 0;
    if (w < 8) ov = op[w * RSTR8 + lane];

    // consume prefetched em; issue next prefetch (token from LDS)
    f32x4 em_now = em_pref;
    {
      const int ln = fwd ? (s + 1 < LL ? s + 1 : LL - 1)
                         : ((LL - 2) - s > 0 ? (LL - 2) - s : 0);
      const int tokn = s_tok[mr * 257 + ln];
      em_pref = *(const f32x4*)(emb + (size_t)tokn * 256 + st);
    }

    // single-product f16 matmul (8 MFMA/wave/step); junk batch cols 8-15
    // compute copies -- never stored.
    f32x4 hh = 0.0f;
#pragma unroll
    for (int kt = 0; kt < 8; ++kt)
      hh = mfma16f(a_hi[kt], bfr[kt], hh);
    f32x4 v  = hh;                     // pre-em matmul result
    f32x4 cn = v * em_now;             // new carry

    u64 p0 = pack4(cn);
    s_carry[wb][m * RSTR8 + 4 * w + q] = p0;        // rows 8-15 = copies
    if (!fwd)
      v_pl[wb][m * RSTR8 + 4 * w + q] = pack4(v);   // g[l] = v

    // coalesced 512B store of the previous step's row (waves 0-7 only)
    if (w < 8)
      *(u64*)(obuf + ((size_t)lp * BB + bg0 + w) * SS + lane * 4) = ov;

    lds_barrier();  // LDS ordering only; global stores/loads stay in flight
  }

  // ---- epilogue: store the final step's row (plane 1 = step 255) ----
  if (w < 8) {
    const int lp = fwd ? (LL - 1) : 0;
    const u64* op = fwd ? &s_carry[1][0] : &v_pl[1][0];
    u64 ov = op[w * RSTR8 + lane];
    *(u64*)(obuf + ((size_t)lp * BB + bg0 + w) * SS + lane * 4) = ov;
  }
}

__global__ __launch_bounds__(256, 2)
void hmm_score(const _Float16* __restrict__ fwh, const _Float16* __restrict__ gh,
               const float* __restrict__ outm, float* __restrict__ score)
{
  __shared__ u64 p_pl[64 * RSTR8];   // p = fw*g, [row][k] f16
  __shared__ u64 o_pl[64 * RSTRO];   // outm^T,   [n][k]  f16

  const int tid  = threadIdx.x;
  const int lane = tid & 63;
  const int w    = tid >> 6;
  const int rh   = w >> 1;     // row half: rows [32rh, 32rh+32)
  const int np   = w & 1;      // n-pair: n-tiles {2np, 2np+1}
  const int m    = lane & 15;
  const int q    = lane >> 4;
  const int R0   = blockIdx.x * 64;  // row = l*128 + b

  // ---- stage outm -> o_pl[n][k] f16 (RNE, hi only), coalesced f32x4 loads
  {
    _Float16* o_h = (_Float16*)o_pl;
    for (int i = tid; i < 4096; i += 256) {
      f32x4 v = *(const f32x4*)(outm + i * 4);   // flat = k*64+n
      int k = i >> 4, n0 = (i & 15) * 4;
#pragma unroll
      for (int r = 0; r < 4; ++r)
        o_h[(n0 + r) * (RSTRO * 4) + k] = (_Float16)v[r];
    }
  }

  // ---- stage p = fw * g (f16 packed mul, RNE) ----
  for (int idx = tid; idx < 64 * 64; idx += 256) {
    int row = idx >> 6, c = idx & 63;       // c = 8B column index
    union { u64 u; half4 h; } a, b, p;
    a.u = *(const u64*)(fwh + (size_t)(R0 + row) * 256 + c * 4);
    b.u = *(const u64*)(gh  + (size_t)(R0 + row) * 256 + c * 4);
    p.h = a.h * b.h;                        // v_pk_mul_f16 x2
    p_pl[row * RSTR8 + c] = p.u;
  }
  lds_barrier();

  f32x4 acc[2][2];
#pragma unroll
  for (int j = 0; j < 2; ++j)
#pragma unroll
    for (int jn = 0; jn < 2; ++jn) acc[j][jn] = 0.0f;

#pragma unroll
  for (int kt = 0; kt < 8; ++kt) {
    half8 of[2];
#pragma unroll
    for (int jn = 0; jn < 2; ++jn)
      of[jn] = read_frag_s(o_pl, 16 * (2 * np + jn) + m, kt, q, RSTRO);
#pragma unroll
    for (int j = 0; j < 2; ++j) {
      half8 pf = read_frag_s(p_pl, 32 * rh + 16 * j + m, kt, q, RSTR8);
#pragma unroll
      for (int jn = 0; jn < 2; ++jn)
        acc[j][jn] = mfma16f(pf, of[jn], acc[j][jn]);
    }
  }

#pragma unroll
  for (int j = 0; j < 2; ++j) {
#pragma unroll
    for (int jn = 0; jn < 2; ++jn) {
#pragma unroll
      for (int r = 0; r < 4; ++r) {
        int row = R0 + 32 * rh + 16 * j + 4 * q + r;
        int l = row >> 7, b = row & 127;
        score[(size_t)b * 16384 + l * 64 + 16 * (2 * np + jn) + m] = acc[j][jn][r];
      }
    }
  }
}

extern "C" void kernel_launch(void* const* d_in, const int* in_sizes, int n_in,
                              void* d_out, int out_size, void* d_ws, size_t ws_size,
                              hipStream_t stream) {
  (void)in_sizes; (void)n_in; (void)out_size; (void)ws_size;
  const int*   sent = (const int*)d_in[0];
  const float* emb  = (const float*)d_in[1];
  const float* T    = (const float*)d_in[2];
  const float* outm = (const float*)d_in[3];
  _Float16* fwh = (_Float16*)d_ws;                  // [L][B][S] f16, 16 MB
  _Float16* gh  = fwh + (size_t)LL * BB * SS;       // [L][B][S] f16, 16 MB

  hmm_chain<<<32, 1024, 0, stream>>>(sent, emb, T, fwh, gh);
  hmm_score<<<512, 256, 0, stream>>>(fwh, gh, outm, (float*)d_out);
}

// Round 13
// 271.408 us; speedup vs baseline: 1.1281x; 1.0093x over previous
//
#include <hip/hip_runtime.h>
#include <hip/hip_bf16.h>

// IO-HMM fwd/bwd chain + projection for MI355X (gfx950).
// L=256 steps, B=128 batch, S=256 states, NL=64 labels.
//
// Kernel 1 (chain): R23 = R22 (BT=8, 32 blocks, 16 waves x 1 M-tile,
//   deferred coalesced stores) + DPP HALF-FRAG reads. Ledger: R20 (half
//   the LDS instrs, neutral) + R22 (half the DISTINCT bytes, neutral)
//   => LDS service is charged per LANE-ACCESS BYTES (~85-128B/cyc/CU);
//   every prior variant kept per-lane bytes constant (128B/lane/step).
//   R23 halves per-lane bytes using R22's duplication: lane pairs
//   (m, m+8) in each 16-lane DPP row need IDENTICAL fragments, so lane m
//   reads only the LOW 8B, lane m+8 only the HIGH 8B (ONE ds_read_b64
//   per frag), and the halves cross lanes via v_mov_b32_dpp row_ror:8
//   (VALU pipe -- free of LDS). Lanes m<8 assemble (low,high) frags
//   bit-identical to R18b; lanes m>=8 end half-swapped = junk, feeding
//   only output cols 8-15 which are never stored. Frag traffic 8KB ->
//   4KB/wave/step. Plane stride 66 u64 (audited: frag reads uniform
//   4/bank-pair = floor; writes <=2-way = free), 8 rows, writes masked
//   m<8. Arithmetic for valid cols bit-identical (absmax 128 expected).
//   If neutral: per-lane bytes exonerated too -> fixed barrier/latency
//   core is the floor -> declare ceiling.
// Kernel 2 (score): R11 version unchanged (gap is timed-region overhead).

typedef _Float16 half8 __attribute__((ext_vector_type(8)));
typedef _Float16 half4 __attribute__((ext_vector_type(4)));
typedef float    f32x4 __attribute__((ext_vector_type(4)));
typedef unsigned long long u64;

#define LL 256
#define BB 128
#define SS 256
#define BT 8      // batch rows per block; 32 blocks (16 fwd + 16 bwd)
#define CSTR 66   // chain plane row stride in u64 units (audited bank floor)
#define RSTR8 67  // score p-plane row stride in 8B units (ODD -> conflict-free)
#define RSTRO 65  // score o-plane row stride in 8B units (ODD -> conflict-free)

static __device__ __forceinline__ f32x4 mfma16f(half8 a, half8 b, f32x4 c) {
  return __builtin_amdgcn_mfma_f32_16x16x32_f16(a, b, c, 0, 0, 0);
}

// LDS-only barrier: order ds ops, leave vmcnt (global loads/stores) in flight.
static __device__ __forceinline__ void lds_barrier() {
  __asm__ __volatile__("s_waitcnt lgkmcnt(0)\n\ts_barrier" ::: "memory");
}

// Round-to-nearest-even f16 pack (NOT cvt_pkrtz -- RTZ bias compounds over
// the 255-step chain into ~6% coherent shrink; R8 erratum).
static __device__ __forceinline__ u64 pack4(f32x4 v) {
  union { half4 h; u64 u; } x;
  x.h[0] = (_Float16)v[0];
  x.h[1] = (_Float16)v[1];
  x.h[2] = (_Float16)v[2];
  x.h[3] = (_Float16)v[3];
  return x.u;
}

// Cross-lane half exchange: lane i <-> lane i^8 within each 16-lane DPP row
// (row_ror:8 is self-inverse at n=8). VALU pipe -- no LDS cost.
static __device__ __forceinline__ u64 dpp_xor8(u64 x) {
  union { u64 u; int i[2]; } a, r;
  a.u = x;
  r.i[0] = __builtin_amdgcn_mov_dpp(a.i[0], 0x128, 0xf, 0xf, true);
  r.i[1] = __builtin_amdgcn_mov_dpp(a.i[1], 0x128, 0xf, 0xf, true);
  return r.u;
}

// Chain B-frag via half-read + DPP: lane (m,q) reads 8B half h=(m>=8) of
// row mr=m&7; partner half arrives by DPP. Lanes m<8: (own=low, par=high)
// = bit-identical frag; lanes m>=8: half-swapped junk (cols 8-15, unused).
static __device__ __forceinline__ half8 read_frag_dpp(const u64* plane, int mr,
                                                      int kt, int q, int h) {
  u64 own = plane[mr * CSTR + kt * 8 + q * 2 + h];
  u64 par = dpp_xor8(own);
  union { u64 u[2]; half8 v; } x;
  x.u[0] = own;
  x.u[1] = par;
  return x.v;
}

// Score-kernel fragment: two b64 reads (8B-aligned odd-stride layout).
static __device__ __forceinline__ half8 read_frag_s(const u64* plane, int row,
                                                    int kt, int q, int stride8) {
  const int o = row * stride8 + kt * 8 + q * 2;
  union { u64 u[2]; half8 v; } x;
  x.u[0] = plane[o];
  x.u[1] = plane[o + 1];
  return x.v;
}

__global__ __launch_bounds__(1024, 4)
void hmm_chain(const int* __restrict__ sent, const float* __restrict__ emb,
               const float* __restrict__ T, _Float16* __restrict__ fwh,
               _Float16* __restrict__ gh)
{
  __shared__ u64 s_carry[2][BT * CSTR]; // [buf][row*stride], 8 rows (batch 0-7)
  __shared__ u64 v_pl[2][BT * CSTR];    // bwd: pack4(v) mirror plane, dbuf
  __shared__ int s_tok[BT * 257];       // [batch][l], stride 257

  const int tid  = threadIdx.x;
  const int lane = tid & 63;
  const int w    = tid >> 6;        // wave 0..15 -> states [16w, 16w+16)
  const int m    = lane & 15;       // A row-in-tile / B col (8-15 junk cols)
  const int mr   = m & 7;           // valid batch row
  const int h    = (lane >> 3) & 1; // which 8B half this lane reads
  const int q    = lane >> 4;       // quad

  const int  bid = blockIdx.x;
  const bool fwd = (bid < 16);
  const int  bg0 = (fwd ? bid : bid - 16) * BT;
  _Float16* const obuf = fwd ? fwh : gh;
  const int  st  = 16 * w + 4 * q;  // this lane's first state

  // ---- stage sentence tokens (BT=8 rows) ----
  for (int idx = tid; idx < BT * LL; idx += 1024) {
    int bb = idx >> 8, l2 = idx & 255;
    s_tok[bb * 257 + l2] = sent[(bg0 + bb) * LL + l2];
  }
  __syncthreads();

  // ---- load T fragments (A operand), single f16: 8 frags = 32 regs
  half8 a_hi[8];
#pragma unroll
  for (int kt = 0; kt < 8; ++kt) {
    const int r0 = 16 * w + m;           // state (M index) -- all rows real
    const int kb = 32 * kt + 8 * q;      // k base
    float v[8];
    if (fwd) {
      f32x4 f0 = *(const f32x4*)(T + r0 * 256 + kb);
      f32x4 f1 = *(const f32x4*)(T + r0 * 256 + kb + 4);
#pragma unroll
      for (int j = 0; j < 4; ++j) { v[j] = f0[j]; v[4 + j] = f1[j]; }
    } else {
#pragma unroll
      for (int j = 0; j < 8; ++j) v[j] = T[(kb + j) * 256 + r0]; // T^T
    }
    half8 hi;
#pragma unroll
    for (int j = 0; j < 8; ++j) hi[j] = (_Float16)v[j];   // RNE
    a_hi[kt] = hi;
  }

  // ---- init carry at l0 (rows 0-7 only); bwd also inits v_pl[0] = 1 ----
  const int l0 = fwd ? 0 : (LL - 1);
  {
    const int tok0 = s_tok[mr * 257 + l0];
    f32x4 e0 = *(const f32x4*)(emb + (size_t)tok0 * 256 + st);
    if (m < 8) {
      u64 pc = pack4(e0);                     // carry = em[l0] both dirs
      s_carry[0][m * CSTR + 4 * w + q] = pc;
      if (!fwd) {
        f32x4 one = 1.0f;
        v_pl[0][m * CSTR + 4 * w + q] = pack4(one);  // g[L-1] = 1
      }
    }
  }

  // ---- prefetch em for step 1 ----
  f32x4 em_pref;
  {
    const int l1 = fwd ? 1 : (LL - 2);
    const int tok1 = s_tok[mr * 257 + l1];
    em_pref = *(const f32x4*)(emb + (size_t)tok1 * 256 + st);
  }
  __syncthreads();

  // ---- main chain ----
  for (int s = 1; s < LL; ++s) {
    const int lp = fwd ? (s - 1) : (LL - s);   // prev step's l
    const int rb = (s - 1) & 1, wb = s & 1;

    const u64* pr = &s_carry[rb][0];
    half8 bfr[8];
#pragma unroll
    for (int kt = 0; kt < 8; ++kt)
      bfr[kt] = read_frag_dpp(pr, mr, kt, q, h);   // 8x b64 + 16 DPP movs

    // deferred out-row read for step s-1 (waves 0-7 only)
    const u64* op = fwd ? &s_carry[rb][0] : &v_pl[rb][0];
    u64 ov = 0;
    if (w < 8) ov = op[w * CSTR + lane];

    // consume prefetched em; issue next prefetch (token from LDS)
    f32x4 em_now = em_pref;
    {
      const int ln = fwd ? (s + 1 < LL ? s + 1 : LL - 1)
                         : ((LL - 2) - s > 0 ? (LL - 2) - s : 0);
      const int tokn = s_tok[mr * 257 + ln];
      em_pref = *(const f32x4*)(emb + (size_t)tokn * 256 + st);
    }

    // single-product f16 matmul (8 MFMA/wave/step); cols 8-15 junk.
    f32x4 hh = 0.0f;
#pragma unroll
    for (int kt = 0; kt < 8; ++kt)
      hh = mfma16f(a_hi[kt], bfr[kt], hh);
    f32x4 v  = hh;                     // pre-em matmul result
    f32x4 cn = v * em_now;             // new carry

    if (m < 8) {
      u64 p0 = pack4(cn);
      s_carry[wb][m * CSTR + 4 * w + q] = p0;
      if (!fwd)
        v_pl[wb][m * CSTR + 4 * w + q] = pack4(v);  // g[l] = v
    }

    // coalesced 512B store of the previous step's row (waves 0-7 only)
    if (w < 8)
      *(u64*)(obuf + ((size_t)lp * BB + bg0 + w) * SS + lane * 4) = ov;

    lds_barrier();  // LDS ordering only; global stores/loads stay in flight
  }

  // ---- epilogue: store the final step's row (plane 1 = step 255) ----
  if (w < 8) {
    const int lp = fwd ? (LL - 1) : 0;
    const u64* op = fwd ? &s_carry[1][0] : &v_pl[1][0];
    u64 ov = op[w * CSTR + lane];
    *(u64*)(obuf + ((size_t)lp * BB + bg0 + w) * SS + lane * 4) = ov;
  }
}

__global__ __launch_bounds__(256, 2)
void hmm_score(const _Float16* __restrict__ fwh, const _Float16* __restrict__ gh,
               const float* __restrict__ outm, float* __restrict__ score)
{
  __shared__ u64 p_pl[64 * RSTR8];   // p = fw*g, [row][k] f16
  __shared__ u64 o_pl[64 * RSTRO];   // outm^T,   [n][k]  f16

  const int tid  = threadIdx.x;
  const int lane = tid & 63;
  const int w    = tid >> 6;
  const int rh   = w >> 1;     // row half: rows [32rh, 32rh+32)
  const int np   = w & 1;      // n-pair: n-tiles {2np, 2np+1}
  const int m    = lane & 15;
  const int q    = lane >> 4;
  const int R0   = blockIdx.x * 64;  // row = l*128 + b

  // ---- stage outm -> o_pl[n][k] f16 (RNE, hi only), coalesced f32x4 loads
  {
    _Float16* o_h = (_Float16*)o_pl;
    for (int i = tid; i < 4096; i += 256) {
      f32x4 v = *(const f32x4*)(outm + i * 4);   // flat = k*64+n
      int k = i >> 4, n0 = (i & 15) * 4;
#pragma unroll
      for (int r = 0; r < 4; ++r)
        o_h[(n0 + r) * (RSTRO * 4) + k] = (_Float16)v[r];
    }
  }

  // ---- stage p = fw * g (f16 packed mul, RNE) ----
  for (int idx = tid; idx < 64 * 64; idx += 256) {
    int row = idx >> 6, c = idx & 63;       // c = 8B column index
    union { u64 u; half4 h; } a, b, p;
    a.u = *(const u64*)(fwh + (size_t)(R0 + row) * 256 + c * 4);
    b.u = *(const u64*)(gh  + (size_t)(R0 + row) * 256 + c * 4);
    p.h = a.h * b.h;                        // v_pk_mul_f16 x2
    p_pl[row * RSTR8 + c] = p.u;
  }
  lds_barrier();

  f32x4 acc[2][2];
#pragma unroll
  for (int j = 0; j < 2; ++j)
#pragma unroll
    for (int jn = 0; jn < 2; ++jn) acc[j][jn] = 0.0f;

#pragma unroll
  for (int kt = 0; kt < 8; ++kt) {
    half8 of[2];
#pragma unroll
    for (int jn = 0; jn < 2; ++jn)
      of[jn] = read_frag_s(o_pl, 16 * (2 * np + jn) + m, kt, q, RSTRO);
#pragma unroll
    for (int j = 0; j < 2; ++j) {
      half8 pf = read_frag_s(p_pl, 32 * rh + 16 * j + m, kt, q, RSTR8);
#pragma unroll
      for (int jn = 0; jn < 2; ++jn)
        acc[j][jn] = mfma16f(pf, of[jn], acc[j][jn]);
    }
  }

#pragma unroll
  for (int j = 0; j < 2; ++j) {
#pragma unroll
    for (int jn = 0; jn < 2; ++jn) {
#pragma unroll
      for (int r = 0; r < 4; ++r) {
        int row = R0 + 32 * rh + 16 * j + 4 * q + r;
        int l = row >> 7, b = row & 127;
        score[(size_t)b * 16384 + l * 64 + 16 * (2 * np + jn) + m] = acc[j][jn][r];
      }
    }
  }
}

extern "C" void kernel_launch(void* const* d_in, const int* in_sizes, int n_in,
                              void* d_out, int out_size, void* d_ws, size_t ws_size,
                              hipStream_t stream) {
  (void)in_sizes; (void)n_in; (void)out_size; (void)ws_size;
  const int*   sent = (const int*)d_in[0];
  const float* emb  = (const float*)d_in[1];
  const float* T    = (const float*)d_in[2];
  const float* outm = (const float*)d_in[3];
  _Float16* fwh = (_Float16*)d_ws;                  // [L][B][S] f16, 16 MB
  _Float16* gh  = fwh + (size_t)LL * BB * SS;       // [L][B][S] f16, 16 MB

  hmm_chain<<<32, 1024, 0, stream>>>(sent, emb, T, fwh, gh);
  hmm_score<<<512, 256, 0, stream>>>(fwh, gh, outm, (float*)d_out);
}